// Round 18
// baseline (2093.557 us; speedup 1.0000x reference)
//
#include <hip/hip_runtime.h>
#include <hip/hip_bf16.h>

// T=512, B=64, D=1024, H=1024, 4H=4096
// Pass 0a: pack Wi -> bf16 hi, MFMA B-fragment slab order (8MB)
// Pass 0b: pack x  -> bf16 hi, MFMA A-fragment slab order (64MB)
// Pass 1 : G2 = x @ Wi + b, single bf16 MFMA pass, both operands gl_lds.
// Pass 2 : cooperative scan (round-17 core). ROUND-18: barrier release is
//          per-wave — all 4 waves poll the 64 class flags in parallel
//          (lane l polls flag l) and proceed WITHOUT a post-poll
//          __syncthreads (arrive-side sync already orders zS/hp hazards).
//          3 -> 2 syncthreads/step; wave h-loads issue at visibility.

typedef __attribute__((ext_vector_type(8))) short bf16x8;
typedef __attribute__((ext_vector_type(8))) unsigned short ushx8;
typedef __attribute__((ext_vector_type(4))) unsigned short ushx4;
typedef __attribute__((ext_vector_type(4))) float f32x4;
typedef __attribute__((ext_vector_type(2))) unsigned long long u64x2;

static __device__ __forceinline__ unsigned short f2bf(float x) {
    __hip_bfloat16 h = __float2bfloat16(x);
    return __builtin_bit_cast(unsigned short, h);
}
static __device__ __forceinline__ float bf2f(unsigned short u) {
    __hip_bfloat16 h = __builtin_bit_cast(__hip_bfloat16, u);
    return __bfloat162float(h);
}

// coherent (agent-scope, L2-bypassing) 16B load as 2 x u64 relaxed atomics
static __device__ __forceinline__ bf16x8 ld_h16(const unsigned long long* p) {
    unsigned long long a = __hip_atomic_load(p,     __ATOMIC_RELAXED, __HIP_MEMORY_SCOPE_AGENT);
    unsigned long long b = __hip_atomic_load(p + 1, __ATOMIC_RELAXED, __HIP_MEMORY_SCOPE_AGENT);
    u64x2 v; v.x = a; v.y = b;
    return __builtin_bit_cast(bf16x8, v);
}

static __device__ __forceinline__ void gl_lds16(const void* g, void* l) {
    __builtin_amdgcn_global_load_lds(
        (const __attribute__((address_space(1))) unsigned int*)g,
        (__attribute__((address_space(3))) unsigned int*)l, 16, 0, 0);
}

static __device__ __forceinline__ float sigm_fast(float x) {
    return 1.f / (1.f + __expf(-x));
}
static __device__ __forceinline__ float tanh_fast(float x) {
    float e = __expf(2.f * x);
    return 1.f - 2.f / (e + 1.f);
}

// ---------------------------------------------------------------------------
// Pass 0a: pack Wi[1024][4096] f32 -> WiHi bf16 (hi only), B-fragment slabs.
// ---------------------------------------------------------------------------
__global__ __launch_bounds__(256)
void wi_pack(const float* __restrict__ Wi, unsigned short* __restrict__ WiHi)
{
    const int bid = blockIdx.x;            // 1024 = tn(32) x kb(32)
    const int tn = bid >> 5, kb = bid & 31;
    const int t = threadIdx.x;
    const int c = t & 127, ko = t >> 7;
    const float* src = Wi + (size_t)(kb * 32 + ko * 16) * 4096 + tn * 128 + c;
    const size_t dbase = ((size_t)(tn * 32 + kb)) * 4096 + c * 8;
#pragma unroll
    for (int o = 0; o < 2; ++o) {
        ushx8 hv;
#pragma unroll
        for (int q = 0; q < 8; ++q)
            hv[q] = f2bf(src[(size_t)(o * 8 + q) * 4096]);
        int kq = ko * 2 + o;
        *(ushx8*)(WiHi + dbase + kq * 1024) = hv;
    }
}

// ---------------------------------------------------------------------------
// Pass 0b: pack x[32768][1024] f32 -> xHi bf16 (hi only), A-fragment slabs.
// ---------------------------------------------------------------------------
__global__ __launch_bounds__(256)
void x_pack(const float* __restrict__ x, unsigned short* __restrict__ xHi)
{
    const int bid = blockIdx.x;            // 8192 = bm(256) x kb(32)
    const int bm = bid >> 5, kb = bid & 31;
    const int t = threadIdx.x;
    const int row = t >> 1, kh = t & 1;
    const float* src = x + (size_t)(bm * 128 + row) * 1024 + kb * 32 + kh * 16;
    const size_t dbase = ((size_t)(bm * 32 + kb)) * 4096 + row * 8;

    float4 f0 = *(const float4*)(src + 0);
    float4 f1 = *(const float4*)(src + 4);
    float4 f2 = *(const float4*)(src + 8);
    float4 f3 = *(const float4*)(src + 12);
    float fs[16] = {f0.x, f0.y, f0.z, f0.w, f1.x, f1.y, f1.z, f1.w,
                    f2.x, f2.y, f2.z, f2.w, f3.x, f3.y, f3.z, f3.w};
#pragma unroll
    for (int o = 0; o < 2; ++o) {
        ushx8 hv;
#pragma unroll
        for (int q = 0; q < 8; ++q) hv[q] = f2bf(fs[o * 8 + q]);
        int kq = kh * 2 + o;
        *(ushx8*)(xHi + dbase + kq * 1024) = hv;
    }
}

// ---------------------------------------------------------------------------
// Pass 1: G2 = x @ Wi + bias; single bf16 pass, both operands global_load_lds.
// ---------------------------------------------------------------------------
__global__ __launch_bounds__(256)
void xwi_gemm_mfma(const unsigned short* __restrict__ xHi,
                   const unsigned short* __restrict__ WiHi,
                   const float* __restrict__ bias,
                   unsigned short* __restrict__ G2)
{
    __shared__ __align__(16) unsigned short AHi[4096];
    __shared__ __align__(16) unsigned short BHi[4096];
    const int bid = blockIdx.x;
    const int bm = bid >> 5, bn = bid & 31;
    const int m0 = bm << 7, n0 = bn << 7;
    const int t = threadIdx.x;
    const int w = t >> 6, l = t & 63, lq = l >> 4, lc = l & 15;
    const int wm = w >> 1, wn = w & 1;

    f32x4 acc[4][4] = {};
    const unsigned short* aSl = xHi + (size_t)(bm * 32) * 4096;
    const unsigned short* bSl = WiHi + (size_t)(bn * 32) * 4096;

    for (int kb = 0; kb < 32; ++kb) {
        {
            const unsigned short* sA = aSl + (size_t)kb * 4096;
            const unsigned short* sB = bSl + (size_t)kb * 4096;
            gl_lds16(sA + (size_t)(w * 128 + l) * 8,      &AHi[(w * 128) * 8]);
            gl_lds16(sA + (size_t)(w * 128 + 64 + l) * 8, &AHi[(w * 128 + 64) * 8]);
            gl_lds16(sB + (size_t)(w * 128 + l) * 8,      &BHi[(w * 128) * 8]);
            gl_lds16(sB + (size_t)(w * 128 + 64 + l) * 8, &BHi[(w * 128 + 64) * 8]);
        }
        __syncthreads();

        bf16x8 xh[4], wh_[4];
#pragma unroll
        for (int a = 0; a < 4; ++a) {
            int off = lq * 1024 + (wm * 64 + a * 16 + lc) * 8;
            xh[a] = *(const bf16x8*)&AHi[off];
        }
#pragma unroll
        for (int b = 0; b < 4; ++b) {
            int off = lq * 1024 + (wn * 64 + b * 16 + lc) * 8;
            wh_[b] = *(const bf16x8*)&BHi[off];
        }
#pragma unroll
        for (int a = 0; a < 4; ++a)
#pragma unroll
            for (int b = 0; b < 4; ++b)
                acc[a][b] = __builtin_amdgcn_mfma_f32_16x16x32_bf16(wh_[b], xh[a], acc[a][b], 0, 0, 0);
        __syncthreads();
    }

    float bv[4][4];
#pragma unroll
    for (int b = 0; b < 4; ++b)
#pragma unroll
        for (int r = 0; r < 4; ++r)
            bv[b][r] = bias[n0 + wn * 64 + b * 16 + lq * 4 + r];
#pragma unroll
    for (int a = 0; a < 4; ++a) {
        int m = m0 + wm * 64 + a * 16 + lc;
        int step = m >> 6, b_abs = m & 63;
        int bh_ = b_abs >> 4, b_l = b_abs & 15;
#pragma unroll
        for (int b = 0; b < 4; ++b) {
            int j_abs = n0 + wn * 64 + b * 16 + lq * 4;
            int gate = j_abs >> 10;
            int hid  = j_abs & 1023;
            int jg_t = hid >> 4, u0 = hid & 15;   // u0 in {0,4,8,12}
            ushx4 sv;
#pragma unroll
            for (int r = 0; r < 4; ++r) sv[r] = f2bf(acc[a][b][r] + bv[b][r]);
            size_t addr = (((size_t)(step * 64 + jg_t) * 4 + bh_) * 1024)
                          + gate * 256 + b_l * 16 + u0;
            *(ushx4*)(G2 + addr) = sv;
        }
    }
}

// ---------------------------------------------------------------------------
// Pass 2: cooperative MFMA scan. 256 WGs x 256 threads (4 waves), 1 WG/CU.
// WG (jg = wgid>>2, bh = wgid&3); per-class 64-WG barrier. ROUND-18:
// per-wave parallel poll release (no post-poll __syncthreads).
// ---------------------------------------------------------------------------
__global__ __launch_bounds__(256, 1)
void lstm_scan_mfma(const unsigned short* __restrict__ G2,
                    const float* __restrict__ Wh,
                    const float* __restrict__ h0, const float* __restrict__ c0,
                    float* __restrict__ out,
                    unsigned int* __restrict__ hp0,
                    unsigned int* __restrict__ hp1,
                    unsigned int* __restrict__ flags)
{
    __shared__ __align__(16) unsigned short WhHiS[65536];  // 128 KB, [gate][frag]
    __shared__ float zS[4 * 4 * 16 * 18];                  // 18.4 KB

    const int t    = threadIdx.x;
    const int wgid = blockIdx.x;         // 0..255
    const int jg   = wgid >> 2;          // 0..63
    const int bh   = wgid & 3;           // 0..3  (batch-quarter class)
    const int kh = t >> 6, l = t & 63, lq = l >> 4, lc = l & 15;

    // Wh slice -> LDS (once): 64 z-cols (cc = gate*16+u), hi only, B-frag order
    for (int idx = t; idx < 65536; idx += 256) {
        int k = idx >> 6, cc = idx & 63;
        int gate = cc >> 4, u = cc & 15;
        int gcol = gate * 1024 + jg * 16 + u;
        float wv = Wh[(size_t)k * 4096 + gcol];
        int pos = gate * 16384 + (((k >> 5) * 64) + (((k >> 3) & 3) * 16 + u)) * 8 + (k & 7);
        WhHiS[pos] = f2bf(wv);
    }

    // init hp0 from h0 (bf16 hi only, sc1 -> IF$): class-partitioned layout
    if (t < 128) {
        int idx = wgid * 128 + t;
        int b = idx >> 9, k = (idx & 511) * 2;
        unsigned short h0s = f2bf(h0[b * 1024 + k]);
        unsigned short h1s = f2bf(h0[b * 1024 + k + 1]);
        int p32 = (((b >> 4) * 128 + (k >> 3)) * 16 + (b & 15)) * 4 + ((k & 7) >> 1);
        __hip_atomic_store(hp0 + p32, (unsigned int)h0s | ((unsigned int)h1s << 16),
                           __ATOMIC_RELAXED, __HIP_MEMORY_SCOPE_AGENT);
    }

    const int b_l = t >> 4, u_el = t & 15;
    const int b_el = bh * 16 + b_l;
    const int j = jg * 16 + u_el;
    float c_state = c0[b_el * 1024 + j];

    // initial barrier: per-class, per-wave parallel poll (lane l -> flag l)
    {
        asm volatile("s_waitcnt vmcnt(0)" ::: "memory");
        __syncthreads();
        if (t == 0)
            __hip_atomic_store(&flags[(bh * 64 + jg) * 32], 1u, __ATOMIC_RELAXED,
                               __HIP_MEMORY_SCOPE_AGENT);
        while (__hip_atomic_load(&flags[(bh * 64 + l) * 32], __ATOMIC_RELAXED,
                                 __HIP_MEMORY_SCOPE_AGENT) < 1u) {}
        asm volatile("" ::: "memory");
    }

    for (int step = 0; step < 512; ++step) {
        const unsigned long long* hH =
            (const unsigned long long*)((step & 1) ? hp1 : hp0);
        unsigned int* nH = (step & 1) ? hp0 : hp1;

        // G2 prefetch: contiguous 2KB/WG panel, 4 x 2B per thread (dense)
        size_t pb = (((size_t)(step * 64 + jg) * 4 + bh) * 1024) + t;
        unsigned short gvi = G2[pb];
        unsigned short gvf = G2[pb + 256];
        unsigned short gvg = G2[pb + 512];
        unsigned short gvo = G2[pb + 768];

        // K-quarter loop: 8 kb, distinct (rows x K-quarter) per wave.
        bf16x8 ah[8];
#pragma unroll
        for (int i = 0; i < 8; ++i) {
            int kb = kh * 8 + i;
            int a64 = ((bh * 128 + kb * 4 + lq) * 16 + lc) * 2;
            ah[i] = ld_h16(hH + a64);
        }

        f32x4 acc[4] = {};
#pragma unroll
        for (int i = 0; i < 8; ++i) {
            int kb = kh * 8 + i;
            int b0 = (kb * 64 + l) * 8;
#pragma unroll
            for (int g = 0; g < 4; ++g) {
                bf16x8 bf = *(const bf16x8*)&WhHiS[g * 16384 + b0];
                acc[g] = __builtin_amdgcn_mfma_f32_16x16x32_bf16(ah[i], bf, acc[g], 0, 0, 0);
            }
        }

        // split-K partial -> zS[kh][g][row][col] (pad 18: <=2-way banks)
#pragma unroll
        for (int g = 0; g < 4; ++g)
#pragma unroll
            for (int r = 0; r < 4; ++r)
                zS[((kh * 4 + g) * 16 + lq * 4 + r) * 18 + lc] = acc[g][r];
        __syncthreads();

        // elementwise: thread owns (b_el, j); sum the 4 K-quarters per gate
        float zi = bf2f(gvi), zf = bf2f(gvf), zg = bf2f(gvg), zo = bf2f(gvo);
#pragma unroll
        for (int q = 0; q < 4; ++q) {
            const float* zq = zS + (q * 4 * 16) * 18;
            zi += zq[(0 * 16 + b_l) * 18 + u_el];
            zf += zq[(1 * 16 + b_l) * 18 + u_el];
            zg += zq[(2 * 16 + b_l) * 18 + u_el];
            zo += zq[(3 * 16 + b_l) * 18 + u_el];
        }

        float ig = sigm_fast(zi);
        float fg = sigm_fast(zf);
        float gg = tanh_fast(zg);
        float og = sigm_fast(zo);

        c_state = fg * c_state + ig * gg;
        float nh = og * tanh_fast(c_state);

        if (step == 511) {
            out[(size_t)step * 65536 + b_el * 1024 + j] = nh;
            break;                      // no publish/barrier needed
        }

        // publish h (bf16 hi only, sc1 -> IF$, class-partitioned layout)
        unsigned int hiw = f2bf(nh);
        unsigned int hi_o = (unsigned int)__shfl_xor((int)hiw, 1);
        if ((t & 1) == 0) {
            int p32 = ((bh * 128 + (j >> 3)) * 16 + b_l) * 4 + ((j & 7) >> 1);
            __hip_atomic_store(nH + p32, (hiw & 0xffffu) | (hi_o << 16),
                               __ATOMIC_RELAXED, __HIP_MEMORY_SCOPE_AGENT);
        }

        // arrive: publishes drained + all waves past elementwise (zS reads
        // done) -> flag. Deferred out store drains at next arrive. Release:
        // EACH WAVE polls the 64 class flags in parallel (lane l -> flag l)
        // and proceeds immediately — no post-poll __syncthreads (the next
        // mid-step __syncthreads orders zS write->read; 2-slot hp invariant
        // unchanged since flags still publish only after the arrive sync).
        asm volatile("s_waitcnt vmcnt(0)" ::: "memory");
        __syncthreads();
        unsigned int target = (unsigned int)(step + 2);
        if (t == 0)
            __hip_atomic_store(&flags[(bh * 64 + jg) * 32], target, __ATOMIC_RELAXED,
                               __HIP_MEMORY_SCOPE_AGENT);
        out[(size_t)step * 65536 + b_el * 1024 + j] = nh;   // drains next step
        while (__hip_atomic_load(&flags[(bh * 64 + l) * 32], __ATOMIC_RELAXED,
                                 __HIP_MEMORY_SCOPE_AGENT) < target) {}
        asm volatile("" ::: "memory");
    }
}

// ---------------------------------------------------------------------------
extern "C" void kernel_launch(void* const* d_in, const int* in_sizes, int n_in,
                              void* d_out, int out_size, void* d_ws, size_t ws_size,
                              hipStream_t stream)
{
    const float* x  = (const float*)d_in[0];
    const float* h0 = (const float*)d_in[1];
    const float* c0 = (const float*)d_in[2];
    const float* Wi = (const float*)d_in[3];
    const float* Wh = (const float*)d_in[4];
    const float* bb = (const float*)d_in[5];
    float* out = (float*)d_out;

    // ws layout: hp0/hp1 (128KB each) | flags 32KB | WiHi 8MB | xHi 64MB | G2 268MB
    unsigned int* hp0 = (unsigned int*)d_ws;
    unsigned int* hp1 = hp0 + 32768;
    unsigned int* flags = hp1 + 32768;          // 256 * 32 u32 = 32KB
    unsigned short* WiHi = (unsigned short*)(flags + 8192);
    unsigned short* xHi = WiHi + 4194304;       // 64MB
    unsigned short* G2 = xHi + 33554432;

    hipMemsetAsync(flags, 0, 8192 * sizeof(unsigned int), stream);
    wi_pack<<<dim3(1024), dim3(256), 0, stream>>>(Wi, WiHi);
    x_pack<<<dim3(8192), dim3(256), 0, stream>>>(x, xHi);
    xwi_gemm_mfma<<<dim3(8192), dim3(256), 0, stream>>>(xHi, WiHi, bb, G2);

    void* args[] = {(void*)&G2, (void*)&Wh, (void*)&h0, (void*)&c0, (void*)&out,
                    (void*)&hp0, (void*)&hp1, (void*)&flags};
    hipLaunchCooperativeKernel(reinterpret_cast<void*>(&lstm_scan_mfma),
                               dim3(256), dim3(256), args, 0, stream);
}

// Round 19
// 1966.712 us; speedup vs baseline: 1.0645x; 1.0645x over previous
//
#include <hip/hip_runtime.h>
#include <hip/hip_bf16.h>

// T=512, B=64, D=1024, H=1024, 4H=4096
// Pass 0a: pack Wi -> bf16 hi, MFMA B-fragment slab order (8MB)
// Pass 0b: pack x  -> bf16 hi, MFMA A-fragment slab order (64MB)
// Pass 1 : G2 = x @ Wi + b, single bf16 MFMA pass, both operands gl_lds.
// Pass 2 : cooperative scan. ROUND-19: barrier reverted to round-17 verified
//          form (wave-0 poll + post-poll syncthreads); h loads switched from
//          2x8B agent-atomic to a single global_load_dwordx4 sc0 sc1 per
//          fragment (halves sc1 request count; system-scope bypass, strictly
//          stronger coherence). vmcnt(0)+sched_barrier before MFMA use.

typedef __attribute__((ext_vector_type(8))) short bf16x8;
typedef __attribute__((ext_vector_type(8))) unsigned short ushx8;
typedef __attribute__((ext_vector_type(4))) unsigned short ushx4;
typedef __attribute__((ext_vector_type(4))) float f32x4;

static __device__ __forceinline__ unsigned short f2bf(float x) {
    __hip_bfloat16 h = __float2bfloat16(x);
    return __builtin_bit_cast(unsigned short, h);
}
static __device__ __forceinline__ float bf2f(unsigned short u) {
    __hip_bfloat16 h = __builtin_bit_cast(__hip_bfloat16, u);
    return __bfloat162float(h);
}

// cache-bypassing 16B load (system scope: misses L1+L2, served by IF$).
// NOTE: result must not be consumed until a following s_waitcnt vmcnt(0)
// (+ sched_barrier(0) to pin register-only consumers — rule #18).
static __device__ __forceinline__ bf16x8 ld_h16_nc(const void* p) {
    bf16x8 r;
    asm volatile("global_load_dwordx4 %0, %1, off sc0 sc1"
                 : "=v"(r) : "v"(p));
    return r;
}

static __device__ __forceinline__ void gl_lds16(const void* g, void* l) {
    __builtin_amdgcn_global_load_lds(
        (const __attribute__((address_space(1))) unsigned int*)g,
        (__attribute__((address_space(3))) unsigned int*)l, 16, 0, 0);
}

static __device__ __forceinline__ float sigm_fast(float x) {
    return 1.f / (1.f + __expf(-x));
}
static __device__ __forceinline__ float tanh_fast(float x) {
    float e = __expf(2.f * x);
    return 1.f - 2.f / (e + 1.f);
}

// ---------------------------------------------------------------------------
// Pass 0a: pack Wi[1024][4096] f32 -> WiHi bf16 (hi only), B-fragment slabs.
// ---------------------------------------------------------------------------
__global__ __launch_bounds__(256)
void wi_pack(const float* __restrict__ Wi, unsigned short* __restrict__ WiHi)
{
    const int bid = blockIdx.x;            // 1024 = tn(32) x kb(32)
    const int tn = bid >> 5, kb = bid & 31;
    const int t = threadIdx.x;
    const int c = t & 127, ko = t >> 7;
    const float* src = Wi + (size_t)(kb * 32 + ko * 16) * 4096 + tn * 128 + c;
    const size_t dbase = ((size_t)(tn * 32 + kb)) * 4096 + c * 8;
#pragma unroll
    for (int o = 0; o < 2; ++o) {
        ushx8 hv;
#pragma unroll
        for (int q = 0; q < 8; ++q)
            hv[q] = f2bf(src[(size_t)(o * 8 + q) * 4096]);
        int kq = ko * 2 + o;
        *(ushx8*)(WiHi + dbase + kq * 1024) = hv;
    }
}

// ---------------------------------------------------------------------------
// Pass 0b: pack x[32768][1024] f32 -> xHi bf16 (hi only), A-fragment slabs.
// ---------------------------------------------------------------------------
__global__ __launch_bounds__(256)
void x_pack(const float* __restrict__ x, unsigned short* __restrict__ xHi)
{
    const int bid = blockIdx.x;            // 8192 = bm(256) x kb(32)
    const int bm = bid >> 5, kb = bid & 31;
    const int t = threadIdx.x;
    const int row = t >> 1, kh = t & 1;
    const float* src = x + (size_t)(bm * 128 + row) * 1024 + kb * 32 + kh * 16;
    const size_t dbase = ((size_t)(bm * 32 + kb)) * 4096 + row * 8;

    float4 f0 = *(const float4*)(src + 0);
    float4 f1 = *(const float4*)(src + 4);
    float4 f2 = *(const float4*)(src + 8);
    float4 f3 = *(const float4*)(src + 12);
    float fs[16] = {f0.x, f0.y, f0.z, f0.w, f1.x, f1.y, f1.z, f1.w,
                    f2.x, f2.y, f2.z, f2.w, f3.x, f3.y, f3.z, f3.w};
#pragma unroll
    for (int o = 0; o < 2; ++o) {
        ushx8 hv;
#pragma unroll
        for (int q = 0; q < 8; ++q) hv[q] = f2bf(fs[o * 8 + q]);
        int kq = kh * 2 + o;
        *(ushx8*)(xHi + dbase + kq * 1024) = hv;
    }
}

// ---------------------------------------------------------------------------
// Pass 1: G2 = x @ Wi + bias; single bf16 pass, both operands global_load_lds.
// ---------------------------------------------------------------------------
__global__ __launch_bounds__(256)
void xwi_gemm_mfma(const unsigned short* __restrict__ xHi,
                   const unsigned short* __restrict__ WiHi,
                   const float* __restrict__ bias,
                   unsigned short* __restrict__ G2)
{
    __shared__ __align__(16) unsigned short AHi[4096];
    __shared__ __align__(16) unsigned short BHi[4096];
    const int bid = blockIdx.x;
    const int bm = bid >> 5, bn = bid & 31;
    const int m0 = bm << 7, n0 = bn << 7;
    const int t = threadIdx.x;
    const int w = t >> 6, l = t & 63, lq = l >> 4, lc = l & 15;
    const int wm = w >> 1, wn = w & 1;

    f32x4 acc[4][4] = {};
    const unsigned short* aSl = xHi + (size_t)(bm * 32) * 4096;
    const unsigned short* bSl = WiHi + (size_t)(bn * 32) * 4096;

    for (int kb = 0; kb < 32; ++kb) {
        {
            const unsigned short* sA = aSl + (size_t)kb * 4096;
            const unsigned short* sB = bSl + (size_t)kb * 4096;
            gl_lds16(sA + (size_t)(w * 128 + l) * 8,      &AHi[(w * 128) * 8]);
            gl_lds16(sA + (size_t)(w * 128 + 64 + l) * 8, &AHi[(w * 128 + 64) * 8]);
            gl_lds16(sB + (size_t)(w * 128 + l) * 8,      &BHi[(w * 128) * 8]);
            gl_lds16(sB + (size_t)(w * 128 + 64 + l) * 8, &BHi[(w * 128 + 64) * 8]);
        }
        __syncthreads();

        bf16x8 xh[4], wh_[4];
#pragma unroll
        for (int a = 0; a < 4; ++a) {
            int off = lq * 1024 + (wm * 64 + a * 16 + lc) * 8;
            xh[a] = *(const bf16x8*)&AHi[off];
        }
#pragma unroll
        for (int b = 0; b < 4; ++b) {
            int off = lq * 1024 + (wn * 64 + b * 16 + lc) * 8;
            wh_[b] = *(const bf16x8*)&BHi[off];
        }
#pragma unroll
        for (int a = 0; a < 4; ++a)
#pragma unroll
            for (int b = 0; b < 4; ++b)
                acc[a][b] = __builtin_amdgcn_mfma_f32_16x16x32_bf16(wh_[b], xh[a], acc[a][b], 0, 0, 0);
        __syncthreads();
    }

    float bv[4][4];
#pragma unroll
    for (int b = 0; b < 4; ++b)
#pragma unroll
        for (int r = 0; r < 4; ++r)
            bv[b][r] = bias[n0 + wn * 64 + b * 16 + lq * 4 + r];
#pragma unroll
    for (int a = 0; a < 4; ++a) {
        int m = m0 + wm * 64 + a * 16 + lc;
        int step = m >> 6, b_abs = m & 63;
        int bh_ = b_abs >> 4, b_l = b_abs & 15;
#pragma unroll
        for (int b = 0; b < 4; ++b) {
            int j_abs = n0 + wn * 64 + b * 16 + lq * 4;
            int gate = j_abs >> 10;
            int hid  = j_abs & 1023;
            int jg_t = hid >> 4, u0 = hid & 15;   // u0 in {0,4,8,12}
            ushx4 sv;
#pragma unroll
            for (int r = 0; r < 4; ++r) sv[r] = f2bf(acc[a][b][r] + bv[b][r]);
            size_t addr = (((size_t)(step * 64 + jg_t) * 4 + bh_) * 1024)
                          + gate * 256 + b_l * 16 + u0;
            *(ushx4*)(G2 + addr) = sv;
        }
    }
}

// ---------------------------------------------------------------------------
// Pass 2: cooperative MFMA scan. 256 WGs x 256 threads (4 waves), 1 WG/CU.
// WG (jg = wgid>>2, bh = wgid&3); per-class 64-WG barrier (round-17 form).
// h loads: single dwordx4 sc0 sc1 per fragment (round-19).
// ---------------------------------------------------------------------------
__global__ __launch_bounds__(256, 1)
void lstm_scan_mfma(const unsigned short* __restrict__ G2,
                    const float* __restrict__ Wh,
                    const float* __restrict__ h0, const float* __restrict__ c0,
                    float* __restrict__ out,
                    unsigned int* __restrict__ hp0,
                    unsigned int* __restrict__ hp1,
                    unsigned int* __restrict__ flags)
{
    __shared__ __align__(16) unsigned short WhHiS[65536];  // 128 KB, [gate][frag]
    __shared__ float zS[4 * 4 * 16 * 18];                  // 18.4 KB

    const int t    = threadIdx.x;
    const int wgid = blockIdx.x;         // 0..255
    const int jg   = wgid >> 2;          // 0..63
    const int bh   = wgid & 3;           // 0..3  (batch-quarter class)
    const int kh = t >> 6, l = t & 63, lq = l >> 4, lc = l & 15;

    // Wh slice -> LDS (once): 64 z-cols (cc = gate*16+u), hi only, B-frag order
    for (int idx = t; idx < 65536; idx += 256) {
        int k = idx >> 6, cc = idx & 63;
        int gate = cc >> 4, u = cc & 15;
        int gcol = gate * 1024 + jg * 16 + u;
        float wv = Wh[(size_t)k * 4096 + gcol];
        int pos = gate * 16384 + (((k >> 5) * 64) + (((k >> 3) & 3) * 16 + u)) * 8 + (k & 7);
        WhHiS[pos] = f2bf(wv);
    }

    // init hp0 from h0 (bf16 hi only, sc1 -> IF$): class-partitioned layout
    if (t < 128) {
        int idx = wgid * 128 + t;
        int b = idx >> 9, k = (idx & 511) * 2;
        unsigned short h0s = f2bf(h0[b * 1024 + k]);
        unsigned short h1s = f2bf(h0[b * 1024 + k + 1]);
        int p32 = (((b >> 4) * 128 + (k >> 3)) * 16 + (b & 15)) * 4 + ((k & 7) >> 1);
        __hip_atomic_store(hp0 + p32, (unsigned int)h0s | ((unsigned int)h1s << 16),
                           __ATOMIC_RELAXED, __HIP_MEMORY_SCOPE_AGENT);
    }

    const int b_l = t >> 4, u_el = t & 15;
    const int b_el = bh * 16 + b_l;
    const int j = jg * 16 + u_el;
    float c_state = c0[b_el * 1024 + j];

    // initial barrier: per-class (64 WGs), wave-0 poll + post sync (round 17)
    {
        asm volatile("s_waitcnt vmcnt(0)" ::: "memory");
        __syncthreads();
        if (t == 0)
            __hip_atomic_store(&flags[(bh * 64 + jg) * 32], 1u, __ATOMIC_RELAXED,
                               __HIP_MEMORY_SCOPE_AGENT);
        if (t < 64)
            while (__hip_atomic_load(&flags[(bh * 64 + t) * 32], __ATOMIC_RELAXED,
                                     __HIP_MEMORY_SCOPE_AGENT) < 1u) {}
        __syncthreads();
        asm volatile("" ::: "memory");
    }

    for (int step = 0; step < 512; ++step) {
        const unsigned short* hS =
            (const unsigned short*)((step & 1) ? hp1 : hp0);
        unsigned int* nH = (step & 1) ? hp0 : hp1;

        // G2 prefetch: contiguous 2KB/WG panel, 4 x 2B per thread (dense)
        size_t pb = (((size_t)(step * 64 + jg) * 4 + bh) * 1024) + t;
        unsigned short gvi = G2[pb];
        unsigned short gvf = G2[pb + 256];
        unsigned short gvg = G2[pb + 512];
        unsigned short gvo = G2[pb + 768];

        // K-quarter loop: 8 fragments per thread, single dwordx4 sc0 sc1 each
        bf16x8 ah[8];
#pragma unroll
        for (int i = 0; i < 8; ++i) {
            int kb = kh * 8 + i;
            int a16 = ((bh * 128 + kb * 4 + lq) * 16 + lc) * 8;
            ah[i] = ld_h16_nc(hS + a16);
        }
        // drain the 8 in-flight loads (and G2 prefetch); pin MFMAs below.
        asm volatile("s_waitcnt vmcnt(0)" ::: "memory");
        __builtin_amdgcn_sched_barrier(0);

        f32x4 acc[4] = {};
#pragma unroll
        for (int i = 0; i < 8; ++i) {
            int kb = kh * 8 + i;
            int b0 = (kb * 64 + l) * 8;
#pragma unroll
            for (int g = 0; g < 4; ++g) {
                bf16x8 bf = *(const bf16x8*)&WhHiS[g * 16384 + b0];
                acc[g] = __builtin_amdgcn_mfma_f32_16x16x32_bf16(ah[i], bf, acc[g], 0, 0, 0);
            }
        }

        // split-K partial -> zS[kh][g][row][col] (pad 18: <=2-way banks)
#pragma unroll
        for (int g = 0; g < 4; ++g)
#pragma unroll
            for (int r = 0; r < 4; ++r)
                zS[((kh * 4 + g) * 16 + lq * 4 + r) * 18 + lc] = acc[g][r];
        __syncthreads();

        // elementwise: thread owns (b_el, j); sum the 4 K-quarters per gate
        float zi = bf2f(gvi), zf = bf2f(gvf), zg = bf2f(gvg), zo = bf2f(gvo);
#pragma unroll
        for (int q = 0; q < 4; ++q) {
            const float* zq = zS + (q * 4 * 16) * 18;
            zi += zq[(0 * 16 + b_l) * 18 + u_el];
            zf += zq[(1 * 16 + b_l) * 18 + u_el];
            zg += zq[(2 * 16 + b_l) * 18 + u_el];
            zo += zq[(3 * 16 + b_l) * 18 + u_el];
        }

        float ig = sigm_fast(zi);
        float fg = sigm_fast(zf);
        float gg = tanh_fast(zg);
        float og = sigm_fast(zo);

        c_state = fg * c_state + ig * gg;
        float nh = og * tanh_fast(c_state);

        if (step == 511) {
            out[(size_t)step * 65536 + b_el * 1024 + j] = nh;
            break;                      // no publish/barrier needed
        }

        // publish h (bf16 hi only, sc1 -> IF$, class-partitioned layout)
        unsigned int hiw = f2bf(nh);
        unsigned int hi_o = (unsigned int)__shfl_xor((int)hiw, 1);
        if ((t & 1) == 0) {
            int p32 = ((bh * 128 + (j >> 3)) * 16 + b_l) * 4 + ((j & 7) >> 1);
            __hip_atomic_store(nH + p32, (hiw & 0xffffu) | (hi_o << 16),
                               __ATOMIC_RELAXED, __HIP_MEMORY_SCOPE_AGENT);
        }

        // per-class barrier (round-17 verified): arrive (publishes drained),
        // deferred out store, wave-0 poll over the 64 class flags, post sync.
        asm volatile("s_waitcnt vmcnt(0)" ::: "memory");
        __syncthreads();
        unsigned int target = (unsigned int)(step + 2);
        if (t == 0)
            __hip_atomic_store(&flags[(bh * 64 + jg) * 32], target, __ATOMIC_RELAXED,
                               __HIP_MEMORY_SCOPE_AGENT);
        out[(size_t)step * 65536 + b_el * 1024 + j] = nh;   // drains next step
        if (t < 64)
            while (__hip_atomic_load(&flags[(bh * 64 + t) * 32], __ATOMIC_RELAXED,
                                     __HIP_MEMORY_SCOPE_AGENT) < target) {}
        __syncthreads();
        asm volatile("" ::: "memory");
    }
}

// ---------------------------------------------------------------------------
extern "C" void kernel_launch(void* const* d_in, const int* in_sizes, int n_in,
                              void* d_out, int out_size, void* d_ws, size_t ws_size,
                              hipStream_t stream)
{
    const float* x  = (const float*)d_in[0];
    const float* h0 = (const float*)d_in[1];
    const float* c0 = (const float*)d_in[2];
    const float* Wi = (const float*)d_in[3];
    const float* Wh = (const float*)d_in[4];
    const float* bb = (const float*)d_in[5];
    float* out = (float*)d_out;

    // ws layout: hp0/hp1 (128KB each) | flags 32KB | WiHi 8MB | xHi 64MB | G2 268MB
    unsigned int* hp0 = (unsigned int*)d_ws;
    unsigned int* hp1 = hp0 + 32768;
    unsigned int* flags = hp1 + 32768;          // 256 * 32 u32 = 32KB
    unsigned short* WiHi = (unsigned short*)(flags + 8192);
    unsigned short* xHi = WiHi + 4194304;       // 64MB
    unsigned short* G2 = xHi + 33554432;

    hipMemsetAsync(flags, 0, 8192 * sizeof(unsigned int), stream);
    wi_pack<<<dim3(1024), dim3(256), 0, stream>>>(Wi, WiHi);
    x_pack<<<dim3(8192), dim3(256), 0, stream>>>(x, xHi);
    xwi_gemm_mfma<<<dim3(8192), dim3(256), 0, stream>>>(xHi, WiHi, bb, G2);

    void* args[] = {(void*)&G2, (void*)&Wh, (void*)&h0, (void*)&c0, (void*)&out,
                    (void*)&hp0, (void*)&hp1, (void*)&flags};
    hipLaunchCooperativeKernel(reinterpret_cast<void*>(&lstm_scan_mfma),
                               dim3(256), dim3(256), args, 0, stream);
}